// Round 14
// baseline (290.769 us; speedup 1.0000x reference)
//
#include <hip/hip_runtime.h>

#define NN 100000      // nodes
#define NE 1600000     // edges
#define NF 128         // in features
#define NH 64          // hidden
#define NC 40          // classes

#define BKN 128                      // nodes per bucket
#define NBK ((NN + BKN - 1) / BKN)   // 782 buckets
#define CH  4096                     // edges per scatter block
#define NCHB ((NE + CH - 1) / CH)    // 391 scatter blocks
#define CAPB 2560                    // slots per bucket region (mean 2046, sigma 45)
#define OFFS (BKN + 1)
#define XTS 68                       // gemm1 X row stride in uints (136 bf16)

typedef short bf16x8 __attribute__((ext_vector_type(8)));
typedef float f32x4  __attribute__((ext_vector_type(4)));

__device__ __forceinline__ unsigned short f2bf(float f) {
    unsigned int u = __builtin_bit_cast(unsigned int, f);
    u += 0x7FFFu + ((u >> 16) & 1u);          // round-to-nearest-even
    return (unsigned short)(u >> 16);
}
__device__ __forceinline__ float bfl(unsigned int u) {
    return __builtin_bit_cast(float, u << 16);
}
__device__ __forceinline__ float bfh(unsigned int u) {
    return __builtin_bit_cast(float, u & 0xFFFF0000u);
}
__device__ __forceinline__ unsigned int pk2(float a, float b) {
    return (unsigned int)f2bf(a) | ((unsigned int)f2bf(b) << 16);
}
// accumulate 4 bf16 (one uint2 = 8B) into a.{x,y,z,w}
__device__ __forceinline__ void add4(float4& a, uint2 v) {
    a.x += bfl(v.x); a.y += bfh(v.x);
    a.z += bfl(v.y); a.w += bfh(v.y);
}

// prep: transpose weights to bf16 col-major, zero gcnt + plane cursors
__global__ __launch_bounds__(256) void prep_wt(const float* __restrict__ W1,
                                               const float* __restrict__ W2,
                                               const float* __restrict__ Wc,
                                               unsigned short* __restrict__ Wt1,
                                               unsigned short* __restrict__ Wt2,
                                               unsigned short* __restrict__ Wtc,
                                               int* __restrict__ gcnt,
                                               int* __restrict__ curs) {
    int t = blockIdx.x * 256 + threadIdx.x;
    if (t < 8192) {                               // 64 x 128
        int j = t >> 7, k = t & 127;
        Wt1[j * 128 + k] = f2bf(W1[k * 64 + j]);
    } else if (t < 8192 + 4096) {                 // 64 x 64
        int u = t - 8192;
        int j = u >> 6, k = u & 63;
        Wt2[j * 64 + k] = f2bf(W2[k * 64 + j]);
    } else if (t < 8192 + 4096 + 3072) {          // 48 x 64
        int u = t - 8192 - 4096;
        int j = u >> 6, k = u & 63;
        Wtc[j * 64 + k] = (j < NC) ? f2bf(Wc[k * NC + j]) : (unsigned short)0;
    } else if (t < 15360 + NBK) {
        gcnt[t - 15360] = 0;
    } else if (t < 15360 + NBK + 16) {
        curs[t - 15360 - NBK] = 0;
    }
}

// ---------------- coarse bucket CSR (fixed-capacity regions) ----------------
// enc = (col & 127) << 24 | row      (row < 2^17)
__global__ __launch_bounds__(256) void bucket_scatter(const int* __restrict__ row,
                                                      const int* __restrict__ col,
                                                      int* __restrict__ gcnt,
                                                      unsigned int* __restrict__ encs) {
    __shared__ int h[NBK];
    __shared__ int loff[NBK];
    __shared__ int cur[NBK];
    __shared__ int gbase[NBK];
    __shared__ unsigned int stage[CH];
    __shared__ unsigned short sbkt[CH];
    int tid = threadIdx.x;
    for (int i = tid; i < NBK; i += 256) h[i] = 0;
    __syncthreads();
    int e0 = blockIdx.x * CH;
    int nval = NE - e0; if (nval > CH) nval = CH;
    int c[16];
    #pragma unroll
    for (int i = 0; i < 16; ++i) {
        int e = e0 + i * 256 + tid;
        c[i] = (e < NE) ? col[e] : -1;
        if (c[i] >= 0) atomicAdd(&h[c[i] >> 7], 1);
    }
    __syncthreads();
    // exclusive scan of h[0..NBK) by wave 0 (13 elems/lane, 64*13=832 >= 782)
    if (tid < 64) {
        int lane = tid, base = lane * 13;
        int pre[13]; int sum = 0;
        #pragma unroll
        for (int j = 0; j < 13; ++j) {
            int idx = base + j;
            int x = (idx < NBK) ? h[idx] : 0;
            pre[j] = sum; sum += x;
        }
        int run = sum;
        #pragma unroll
        for (int d = 1; d < 64; d <<= 1) {
            int n = __shfl_up(run, d, 64);
            if (lane >= d) run += n;
        }
        int lex = run - sum;
        #pragma unroll
        for (int j = 0; j < 13; ++j) {
            int idx = base + j;
            if (idx < NBK) { loff[idx] = lex + pre[j]; cur[idx] = lex + pre[j]; }
        }
    }
    __syncthreads();
    for (int i = tid; i < NBK; i += 256) {
        int cnt = h[i];
        gbase[i] = cnt ? atomicAdd(&gcnt[i], cnt) : 0;
    }
    __syncthreads();
    #pragma unroll
    for (int i = 0; i < 16; ++i) {
        int e = e0 + i * 256 + tid;
        if (e < NE) {
            int cc = c[i], b = cc >> 7;
            int r = atomicAdd(&cur[b], 1);
            stage[r] = ((unsigned int)(cc & 127) << 24) | (unsigned int)row[e];
            sbkt[r] = (unsigned short)b;
        }
    }
    __syncthreads();
    for (int s = tid; s < nval; s += 256) {
        int b = sbkt[s];
        encs[(size_t)b * CAPB + gbase[b] + (s - loff[b])] = stage[s];
    }
}

// ---------------- csr_sort: node-sort each bucket IN PLACE, emit off + dinv ----------------
__global__ __launch_bounds__(256) void csr_sort(unsigned int* __restrict__ encs,
                                                const int* __restrict__ gcnt,
                                                int* __restrict__ offg,
                                                float* __restrict__ dinv) {
    __shared__ unsigned int sseg[CAPB];
    __shared__ int h[BKN];
    __shared__ int off[OFFS];
    __shared__ int cur[BKN];
    int b = blockIdx.x, tid = threadIdx.x;
    if (tid < BKN) h[tid] = 0;
    __syncthreads();
    int m = gcnt[b];
    unsigned int* seg = encs + (size_t)b * CAPB;
    for (int s = tid; s < m; s += 256) {
        unsigned int e = seg[s];
        sseg[s] = e;
        atomicAdd(&h[e >> 24], 1);
    }
    __syncthreads();
    if (tid < BKN) {
        int g = b * BKN + tid;
        if (g < NN) dinv[g] = rsqrtf((float)(h[tid] + 1));   // +1 self loop
    }
    if (tid < 64) {
        int lane = tid;
        int x0 = h[lane * 2], x1 = h[lane * 2 + 1];
        int sum = x0 + x1, run = sum;
        #pragma unroll
        for (int d = 1; d < 64; d <<= 1) {
            int n = __shfl_up(run, d, 64);
            if (lane >= d) run += n;
        }
        int ex = run - sum;
        off[lane * 2] = ex;          cur[lane * 2] = ex;
        off[lane * 2 + 1] = ex + x0; cur[lane * 2 + 1] = ex + x0;
        if (lane == 63) off[BKN] = run;
    }
    __syncthreads();
    for (int s = tid; s < m; s += 256) {
        unsigned int e = sseg[s];
        int n = e >> 24;
        int r = atomicAdd(&cur[n], 1);
        seg[r] = e & 0xFFFFFFu;
    }
    if (tid < OFFS) offg[b * OFFS + tid] = off[tid];
}

// ---------------- layer-1 GEMM via MFMA -> plane layout ----------------
// hsbT plane p (p=feat/8) holds node r's features [p*8, p*8+8) as 16B at
// hsbT[p*NN + r]. Block = 64 rows, 256 threads = 4 waves.
__global__ __launch_bounds__(256) void gemm1_mfma(const float* __restrict__ x,
                                                  const unsigned short* __restrict__ Wt1,
                                                  const float* __restrict__ dinv,
                                                  uint4* __restrict__ hsbT) {
    __shared__ unsigned int Xl[64 * XTS];        // 17.4 KB packed bf16
    __shared__ float sdv[64];
    int tid = threadIdx.x;
    int rbase = blockIdx.x * 64;
    if (tid < 64) {
        int r = rbase + tid;
        sdv[tid] = (r < NN) ? dinv[r] : 0.f;
    }
    #pragma unroll
    for (int p = 0; p < 8; ++p) {
        int fid = p * 256 + tid;                 // 0..2047 float4s
        int m = fid >> 5, c4 = fid & 31;
        int rr = rbase + m; if (rr >= NN) rr = NN - 1;
        float4 v = *(const float4*)(x + (size_t)rr * NF + c4 * 4);
        uint2 u;
        u.x = pk2(v.x, v.y);
        u.y = pk2(v.z, v.w);
        *(uint2*)&Xl[m * XTS + c4 * 2] = u;
    }
    __syncthreads();

    int wid = tid >> 6, lane = tid & 63;
    int lm = lane & 15, lg = lane >> 4;
    bf16x8 af[4];
    #pragma unroll
    for (int kh = 0; kh < 4; ++kh)
        af[kh] = __builtin_bit_cast(bf16x8,
                    *(const uint4*)&Xl[(wid * 16 + lm) * XTS + kh * 16 + lg * 4]);
    f32x4 acc[4];
    #pragma unroll
    for (int ct = 0; ct < 4; ++ct) {
        acc[ct] = (f32x4){0.f, 0.f, 0.f, 0.f};
        #pragma unroll
        for (int kh = 0; kh < 4; ++kh) {
            bf16x8 bf = __builtin_bit_cast(bf16x8,
                *(const uint4*)(Wt1 + (size_t)(ct * 16 + lm) * 128 + kh * 32 + lg * 8));
            acc[ct] = __builtin_amdgcn_mfma_f32_16x16x32_bf16(af[kh], bf, acc[ct], 0, 0, 0);
        }
    }
    __syncthreads();                             // all Xl reads done; reuse as out-tile
    unsigned short* ot = (unsigned short*)Xl;    // [64 rows][stride 72 shorts]
    #pragma unroll
    for (int ct = 0; ct < 4; ++ct)
        #pragma unroll
        for (int rg = 0; rg < 4; ++rg) {
            int rloc = wid * 16 + lg * 4 + rg;
            ot[rloc * 72 + ct * 16 + lm] = f2bf(acc[ct][rg] * sdv[rloc]);
        }
    __syncthreads();
    unsigned int* otU = (unsigned int*)Xl;
    for (int j = tid; j < 512; j += 256) {       // 8 planes x 64 nodes
        int p = j >> 6, i = j & 63;
        int r = rbase + i;
        if (r < NN)
            hsbT[(size_t)p * NN + r] = *(uint4*)&otU[i * 36 + p * 4];
    }
}

// ---------------- plane-input GEMM via MFMA ----------------
// FINAL=0: hsbT_out[p][r] = bf16((h @ W2) * dinv)   (planes)
// FINAL=1: f_out[r][c]    = (h @ Wc) + biasB[c]     (fp32 rows, c < 40)
template <int FINAL>
__global__ __launch_bounds__(256) void gemm_planes(const uint4* __restrict__ hT,
                                                   const unsigned short* __restrict__ Wt,
                                                   const float* __restrict__ dinv,
                                                   const float* __restrict__ biasB,
                                                   uint4* __restrict__ hsbT_out,
                                                   float* __restrict__ f_out) {
    __shared__ unsigned int ot[64 * 36 + 16];
    int tid = threadIdx.x, rbase = blockIdx.x * 64;
    int wid = tid >> 6, lane = tid & 63;
    int lm = lane & 15, lg = lane >> 4;
    int arow = rbase + wid * 16 + lm; if (arow >= NN) arow = NN - 1;
    bf16x8 af[2];
    #pragma unroll
    for (int kh = 0; kh < 2; ++kh) {
        int p = kh * 4 + lg;                     // features kh*32+lg*8 .. +8
        af[kh] = __builtin_bit_cast(bf16x8, hT[(size_t)p * NN + arow]);
    }
    constexpr int NCT = FINAL ? 3 : 4;
    f32x4 acc[NCT];
    #pragma unroll
    for (int ct = 0; ct < NCT; ++ct) {
        acc[ct] = (f32x4){0.f, 0.f, 0.f, 0.f};
        #pragma unroll
        for (int kh = 0; kh < 2; ++kh) {
            bf16x8 bf = __builtin_bit_cast(bf16x8,
                *(const uint4*)(Wt + (size_t)(ct * 16 + lm) * 64 + kh * 32 + lg * 8));
            acc[ct] = __builtin_amdgcn_mfma_f32_16x16x32_bf16(af[kh], bf, acc[ct], 0, 0, 0);
        }
    }

    if (!FINAL) {
        unsigned short* ots = (unsigned short*)ot;
        #pragma unroll
        for (int ct = 0; ct < NCT; ++ct)
            #pragma unroll
            for (int rg = 0; rg < 4; ++rg) {
                int rloc = wid * 16 + lg * 4 + rg;
                int r = rbase + rloc;
                float d = (r < NN) ? dinv[r] : 0.f;
                ots[rloc * 72 + ct * 16 + lm] = f2bf(acc[ct][rg] * d);
            }
        __syncthreads();
        for (int j = tid; j < 512; j += 256) {
            int p = j >> 6, i = j & 63;
            int r = rbase + i;
            if (r < NN)
                hsbT_out[(size_t)p * NN + r] = *(uint4*)&ot[i * 36 + p * 4];
        }
    } else {
        #pragma unroll
        for (int ct = 0; ct < NCT; ++ct) {
            int c = ct * 16 + lm;
            if (c < NC) {
                float bb = biasB[c];
                #pragma unroll
                for (int rg = 0; rg < 4; ++rg) {
                    int r = rbase + wid * 16 + lg * 4 + rg;
                    if (r < NN)
                        f_out[(size_t)r * NC + c] = acc[ct][rg] + bb;
                }
            }
        }
    }
}

// ---------------- XCD-sliced aggregation ----------------
// Block claims (bucket, plane) with plane == its physical XCD (HW_REG_XCC_ID),
// via per-plane cursors + work-stealing fallback (exact coverage regardless of
// dispatch). Per-XCD working set = one 1.6 MB plane -> L2-resident gathers.
// 256 threads = 128 teams of 2 lanes; team owns node, lane = 8B half-chunk.
// out plane: hT_out[(q*NN+g)*2+l] = bf16x4(relu(dinv*sum + biasA))
__global__ __launch_bounds__(256) void agg_sliced(const uint2* __restrict__ hsbT,
                                                  const unsigned int* __restrict__ encs,
                                                  const int* __restrict__ offg,
                                                  const float* __restrict__ dinv,
                                                  const float* __restrict__ biasA,
                                                  uint2* __restrict__ hT_out,
                                                  int* __restrict__ curs) {
    __shared__ int sbq;
    int tid = threadIdx.x;
    if (tid == 0) {
        int xcc;
        asm volatile("s_getreg_b32 %0, hwreg(HW_REG_XCC_ID)" : "=s"(xcc));
        int q0 = xcc & 7, q = q0, b = NBK;
        #pragma unroll 1
        for (int t = 0; t < 8; ++t) {
            q = (q0 + t) & 7;
            b = atomicAdd(&curs[q], 1);
            if (b < NBK) break;
        }
        sbq = (b < NBK) ? (b * 8 + q) : -1;
    }
    __syncthreads();
    int bq = sbq;
    if (bq < 0) return;
    int b = bq >> 3, q = bq & 7;
    int team = tid >> 1, l = tid & 1;
    int g = b * BKN + team;
    if (g >= NN) return;
    const uint2* pl = hsbT + (size_t)q * NN * 2;
    int e  = offg[b * OFFS + team];
    int ee = offg[b * OFFS + team + 1];
    const unsigned int* sp = encs + (size_t)b * CAPB;
    float4 A0 = {}, A1 = {};
    add4(A0, pl[(size_t)g * 2 + l]);             // self loop
    for (; e + 8 <= ee; e += 8) {
        int r0 = sp[e + 0], r1 = sp[e + 1], r2 = sp[e + 2], r3 = sp[e + 3];
        int r4 = sp[e + 4], r5 = sp[e + 5], r6 = sp[e + 6], r7 = sp[e + 7];
        uint2 v0 = pl[(size_t)r0 * 2 + l], v1 = pl[(size_t)r1 * 2 + l];
        uint2 v2 = pl[(size_t)r2 * 2 + l], v3 = pl[(size_t)r3 * 2 + l];
        uint2 v4 = pl[(size_t)r4 * 2 + l], v5 = pl[(size_t)r5 * 2 + l];
        uint2 v6 = pl[(size_t)r6 * 2 + l], v7 = pl[(size_t)r7 * 2 + l];
        add4(A0, v0); add4(A1, v1); add4(A0, v2); add4(A1, v3);
        add4(A0, v4); add4(A1, v5); add4(A0, v6); add4(A1, v7);
    }
    if (e + 4 <= ee) {
        int r0 = sp[e + 0], r1 = sp[e + 1], r2 = sp[e + 2], r3 = sp[e + 3];
        uint2 v0 = pl[(size_t)r0 * 2 + l], v1 = pl[(size_t)r1 * 2 + l];
        uint2 v2 = pl[(size_t)r2 * 2 + l], v3 = pl[(size_t)r3 * 2 + l];
        add4(A0, v0); add4(A1, v1); add4(A0, v2); add4(A1, v3);
        e += 4;
    }
    for (; e < ee; ++e)
        add4(A0, pl[(size_t)sp[e] * 2 + l]);
    A0.x += A1.x; A0.y += A1.y; A0.z += A1.z; A0.w += A1.w;
    float d = dinv[g];
    float4 bb = *(const float4*)(biasA + q * 8 + l * 4);
    float4 o;
    o.x = fmaxf(fmaf(A0.x, d, bb.x), 0.f);
    o.y = fmaxf(fmaf(A0.y, d, bb.y), 0.f);
    o.z = fmaxf(fmaf(A0.z, d, bb.z), 0.f);
    o.w = fmaxf(fmaf(A0.w, d, bb.w), 0.f);
    uint2 pkv;
    pkv.x = pk2(o.x, o.y);
    pkv.y = pk2(o.z, o.w);
    hT_out[((size_t)q * NN + g) * 2 + l] = pkv;
}

// ---------------- launch ----------------

extern "C" void kernel_launch(void* const* d_in, const int* in_sizes, int n_in,
                              void* d_out, int out_size, void* d_ws, size_t ws_size,
                              hipStream_t stream) {
    const float* x  = (const float*)d_in[0];
    const int* ei   = (const int*)d_in[1];      // [2, NE]
    const int* row  = ei;
    const int* col  = ei + NE;
    const float* W1 = (const float*)d_in[2];
    const float* b1 = (const float*)d_in[3];
    const float* W2 = (const float*)d_in[4];
    const float* b2 = (const float*)d_in[5];
    const float* Wc = (const float*)d_in[6];
    const float* bc = (const float*)d_in[7];
    float* out = (float*)d_out;

    char* ws = (char*)d_ws;
    size_t off = 0;
    auto alloc = [&](size_t bytes) {
        void* p = ws + off;
        off = (off + bytes + 255) & ~(size_t)255;
        return p;
    };
    int*   gcnt = (int*)alloc((size_t)NBK * 4);
    int*   curs = (int*)alloc(64);                                       // 2 x 8 cursors
    int*   offg = (int*)alloc((size_t)NBK * OFFS * 4);
    float* dinv = (float*)alloc((size_t)NN * 4);
    unsigned int* encs = (unsigned int*)alloc((size_t)NBK * CAPB * 4);   // 8 MB
    uint4* hsbT1 = (uint4*)alloc((size_t)NN * NH * 2);   // plane-major bf16
    uint4* hsbT2 = (uint4*)alloc((size_t)NN * NH * 2);
    uint4* h1T   = (uint4*)alloc((size_t)NN * NH * 2);
    uint4* h2T   = (uint4*)alloc((size_t)NN * NH * 2);
    unsigned short* Wt1 = (unsigned short*)alloc((size_t)64 * 128 * 2);
    unsigned short* Wt2 = (unsigned short*)alloc((size_t)64 * 64 * 2);
    unsigned short* Wtc = (unsigned short*)alloc((size_t)48 * 64 * 2);

    const int GB = (NN + 63) / 64;               // 1563

    prep_wt<<<64, 256, 0, stream>>>(W1, W2, Wc, Wt1, Wt2, Wtc, gcnt, curs);
    bucket_scatter<<<NCHB, 256, 0, stream>>>(row, col, gcnt, encs);
    csr_sort<<<NBK, 256, 0, stream>>>(encs, gcnt, offg, dinv);

    // layer 1 GEMM (MFMA): hsbT1 planes = bf16((x @ W1) * dinv)
    gemm1_mfma<<<GB, 256, 0, stream>>>(x, Wt1, dinv, hsbT1);
    // aggregate layer 1 (XCD-sliced): h1T planes = relu(dinv*agg + b1)
    agg_sliced<<<NBK * 8, 256, 0, stream>>>((const uint2*)hsbT1, encs, offg, dinv,
                                            b1, (uint2*)h1T, curs);
    // layer 2 GEMM: hsbT2 planes = bf16((h1 @ W2) * dinv)
    gemm_planes<0><<<GB, 256, 0, stream>>>(h1T, Wt2, dinv, nullptr, hsbT2, nullptr);
    // aggregate layer 2: h2T planes = relu(dinv*agg + b2)
    agg_sliced<<<NBK * 8, 256, 0, stream>>>((const uint2*)hsbT2, encs, offg, dinv,
                                            b2, (uint2*)h2T, curs + 8);
    // classifier: out = h2 @ Wc + bc
    gemm_planes<1><<<GB, 256, 0, stream>>>(h2T, Wtc, nullptr, bc, nullptr, out);
}

// Round 15
// 157.032 us; speedup vs baseline: 1.8517x; 1.8517x over previous
//
#include <hip/hip_runtime.h>

#define NN 100000      // nodes
#define NE 1600000     // edges
#define NF 128         // in features
#define NH 64          // hidden
#define NC 40          // classes

#define BKN 128                      // nodes per bucket
#define NBK ((NN + BKN - 1) / BKN)   // 782 buckets
#define CH  4096                     // edges per scatter block
#define NCHB ((NE + CH - 1) / CH)    // 391 scatter blocks
#define CAPB 2560                    // slots per bucket region (mean 2046, sigma 45)
#define OFFS (BKN + 1)
#define HCAP 1408                    // max edges per 64-node half-bucket (mean 1023, +12 sigma)
#define XTS 68                       // gemm1 X row stride in uints (136 bf16)

typedef short bf16x8 __attribute__((ext_vector_type(8)));
typedef float f32x4  __attribute__((ext_vector_type(4)));

__device__ __forceinline__ unsigned short f2bf(float f) {
    unsigned int u = __builtin_bit_cast(unsigned int, f);
    u += 0x7FFFu + ((u >> 16) & 1u);          // round-to-nearest-even
    return (unsigned short)(u >> 16);
}
__device__ __forceinline__ float bfl(unsigned int u) {
    return __builtin_bit_cast(float, u << 16);
}
__device__ __forceinline__ float bfh(unsigned int u) {
    return __builtin_bit_cast(float, u & 0xFFFF0000u);
}
__device__ __forceinline__ unsigned int pk2(float a, float b) {
    return (unsigned int)f2bf(a) | ((unsigned int)f2bf(b) << 16);
}
// accumulate 8 bf16 (one uint4 = 16B) into lo{f0,f2,f4,f6} / hi{f1,f3,f5,f7}
__device__ __forceinline__ void bacc8(float4& lo, float4& hi, uint4 v) {
    lo.x += bfl(v.x); hi.x += bfh(v.x);
    lo.y += bfl(v.y); hi.y += bfh(v.y);
    lo.z += bfl(v.z); hi.z += bfh(v.z);
    lo.w += bfl(v.w); hi.w += bfh(v.w);
}

// prep: zero gcnt + transpose all weights to bf16 col-major
__global__ __launch_bounds__(256) void prep_wt(const float* __restrict__ W1,
                                               const float* __restrict__ W2,
                                               const float* __restrict__ Wc,
                                               unsigned short* __restrict__ Wt1,
                                               unsigned short* __restrict__ Wt2,
                                               unsigned short* __restrict__ Wtc,
                                               int* __restrict__ gcnt) {
    int t = blockIdx.x * 256 + threadIdx.x;
    if (t < 8192) {                               // 64 x 128
        int j = t >> 7, k = t & 127;
        Wt1[j * 128 + k] = f2bf(W1[k * 64 + j]);
    } else if (t < 8192 + 4096) {                 // 64 x 64
        int u = t - 8192;
        int j = u >> 6, k = u & 63;
        Wt2[j * 64 + k] = f2bf(W2[k * 64 + j]);
    } else if (t < 8192 + 4096 + 3072) {          // 48 x 64
        int u = t - 8192 - 4096;
        int j = u >> 6, k = u & 63;
        Wtc[j * 64 + k] = (j < NC) ? f2bf(Wc[k * NC + j]) : (unsigned short)0;
    } else if (t < 8192 + 4096 + 3072 + NBK) {
        gcnt[t - 8192 - 4096 - 3072] = 0;
    }
}

// ---------------- coarse bucket CSR (fixed-capacity regions) ----------------
// enc = (col & 127) << 24 | row      (row < 2^17)
__global__ __launch_bounds__(256) void bucket_scatter(const int* __restrict__ row,
                                                      const int* __restrict__ col,
                                                      int* __restrict__ gcnt,
                                                      unsigned int* __restrict__ encs) {
    __shared__ int h[NBK];
    __shared__ int loff[NBK];
    __shared__ int cur[NBK];
    __shared__ int gbase[NBK];
    __shared__ unsigned int stage[CH];
    __shared__ unsigned short sbkt[CH];
    int tid = threadIdx.x;
    for (int i = tid; i < NBK; i += 256) h[i] = 0;
    __syncthreads();
    int e0 = blockIdx.x * CH;
    int nval = NE - e0; if (nval > CH) nval = CH;
    int c[16];
    #pragma unroll
    for (int i = 0; i < 16; ++i) {
        int e = e0 + i * 256 + tid;
        c[i] = (e < NE) ? col[e] : -1;
        if (c[i] >= 0) atomicAdd(&h[c[i] >> 7], 1);
    }
    __syncthreads();
    // exclusive scan of h[0..NBK) by wave 0 (13 elems/lane, 64*13=832 >= 782)
    if (tid < 64) {
        int lane = tid, base = lane * 13;
        int pre[13]; int sum = 0;
        #pragma unroll
        for (int j = 0; j < 13; ++j) {
            int idx = base + j;
            int x = (idx < NBK) ? h[idx] : 0;
            pre[j] = sum; sum += x;
        }
        int run = sum;
        #pragma unroll
        for (int d = 1; d < 64; d <<= 1) {
            int n = __shfl_up(run, d, 64);
            if (lane >= d) run += n;
        }
        int lex = run - sum;
        #pragma unroll
        for (int j = 0; j < 13; ++j) {
            int idx = base + j;
            if (idx < NBK) { loff[idx] = lex + pre[j]; cur[idx] = lex + pre[j]; }
        }
    }
    __syncthreads();
    for (int i = tid; i < NBK; i += 256) {
        int cnt = h[i];
        gbase[i] = cnt ? atomicAdd(&gcnt[i], cnt) : 0;
    }
    __syncthreads();
    #pragma unroll
    for (int i = 0; i < 16; ++i) {
        int e = e0 + i * 256 + tid;
        if (e < NE) {
            int cc = c[i], b = cc >> 7;
            int r = atomicAdd(&cur[b], 1);
            stage[r] = ((unsigned int)(cc & 127) << 24) | (unsigned int)row[e];
            sbkt[r] = (unsigned short)b;
        }
    }
    __syncthreads();
    for (int s = tid; s < nval; s += 256) {
        int b = sbkt[s];
        encs[(size_t)b * CAPB + gbase[b] + (s - loff[b])] = stage[s];
    }
}

// ---------------- csr_sort: node-sort each bucket IN PLACE, emit off + dinv ----------------
__global__ __launch_bounds__(256) void csr_sort(unsigned int* __restrict__ encs,
                                                const int* __restrict__ gcnt,
                                                int* __restrict__ offg,
                                                float* __restrict__ dinv) {
    __shared__ unsigned int sseg[CAPB];
    __shared__ int h[BKN];
    __shared__ int off[OFFS];
    __shared__ int cur[BKN];
    int b = blockIdx.x, tid = threadIdx.x;
    if (tid < BKN) h[tid] = 0;
    __syncthreads();
    int m = gcnt[b];
    unsigned int* seg = encs + (size_t)b * CAPB;
    for (int s = tid; s < m; s += 256) {
        unsigned int e = seg[s];
        sseg[s] = e;
        atomicAdd(&h[e >> 24], 1);
    }
    __syncthreads();
    if (tid < BKN) {
        int g = b * BKN + tid;
        if (g < NN) dinv[g] = rsqrtf((float)(h[tid] + 1));   // +1 self loop
    }
    if (tid < 64) {
        int lane = tid;
        int x0 = h[lane * 2], x1 = h[lane * 2 + 1];
        int sum = x0 + x1, run = sum;
        #pragma unroll
        for (int d = 1; d < 64; d <<= 1) {
            int n = __shfl_up(run, d, 64);
            if (lane >= d) run += n;
        }
        int ex = run - sum;
        off[lane * 2] = ex;          cur[lane * 2] = ex;
        off[lane * 2 + 1] = ex + x0; cur[lane * 2 + 1] = ex + x0;
        if (lane == 63) off[BKN] = run;
    }
    __syncthreads();
    for (int s = tid; s < m; s += 256) {
        unsigned int e = sseg[s];
        int n = e >> 24;
        int r = atomicAdd(&cur[n], 1);
        seg[r] = e & 0xFFFFFFu;
    }
    if (tid < OFFS) offg[b * OFFS + tid] = off[tid];
}

// ---------------- layer-1 GEMM via MFMA: hsb1 = bf16((x @ W1) * dinv) ----------------
__global__ __launch_bounds__(256) void gemm1_mfma(const float* __restrict__ x,
                                                  const unsigned short* __restrict__ Wt1,
                                                  const float* __restrict__ dinv,
                                                  unsigned short* __restrict__ hsb) {
    __shared__ unsigned int Xl[64 * XTS];        // 17.4 KB packed bf16
    __shared__ float sdv[64];
    int tid = threadIdx.x;
    int rbase = blockIdx.x * 64;
    if (tid < 64) {
        int r = rbase + tid;
        sdv[tid] = (r < NN) ? dinv[r] : 0.f;
    }
    #pragma unroll
    for (int p = 0; p < 8; ++p) {
        int fid = p * 256 + tid;                 // 0..2047 float4s
        int m = fid >> 5, c4 = fid & 31;
        int rr = rbase + m; if (rr >= NN) rr = NN - 1;
        float4 v = *(const float4*)(x + (size_t)rr * NF + c4 * 4);
        uint2 u;
        u.x = pk2(v.x, v.y);
        u.y = pk2(v.z, v.w);
        *(uint2*)&Xl[m * XTS + c4 * 2] = u;
    }
    __syncthreads();

    int wid = tid >> 6, lane = tid & 63;
    int lm = lane & 15, lg = lane >> 4;
    bf16x8 af[4];
    #pragma unroll
    for (int kh = 0; kh < 4; ++kh)
        af[kh] = __builtin_bit_cast(bf16x8,
                    *(const uint4*)&Xl[(wid * 16 + lm) * XTS + kh * 16 + lg * 4]);
    f32x4 acc[4];
    #pragma unroll
    for (int ct = 0; ct < 4; ++ct) {
        acc[ct] = (f32x4){0.f, 0.f, 0.f, 0.f};
        #pragma unroll
        for (int kh = 0; kh < 4; ++kh) {
            bf16x8 bf = __builtin_bit_cast(bf16x8,
                *(const uint4*)(Wt1 + (size_t)(ct * 16 + lm) * 128 + kh * 32 + lg * 8));
            acc[ct] = __builtin_amdgcn_mfma_f32_16x16x32_bf16(af[kh], bf, acc[ct], 0, 0, 0);
        }
    }
    #pragma unroll
    for (int ct = 0; ct < 4; ++ct) {
        #pragma unroll
        for (int rg = 0; rg < 4; ++rg) {
            int rloc = wid * 16 + lg * 4 + rg;
            int r = rbase + rloc;
            if (r < NN)
                hsb[(size_t)r * NH + ct * 16 + lm] = f2bf(acc[ct][rg] * sdv[rloc]);
        }
    }
}

// ---------------- aggregation (r8 structure): 8-lane-subgroup bf16 gather ----------------
// Block = HALF bucket (64 nodes), 256 threads = 4 waves x 8 subgroups of 8 lanes.
// Subgroup owns a node; lane = feature octet (uint4 = 16B). Unroll 8.
// Output: bf16 rows  hb_out[g][feat] = bf16(relu(dinv*agg + bias))
__global__ __launch_bounds__(256) void agg_bucket(const unsigned short* __restrict__ hs,
                                                  const int* __restrict__ srow,
                                                  const int* __restrict__ offg,
                                                  const float* __restrict__ dinv,
                                                  const float* __restrict__ bias,
                                                  unsigned short* __restrict__ hb_out) {
    __shared__ int off[65];
    __shared__ int sidx[HCAP];
    int b = blockIdx.x >> 1, half = blockIdx.x & 1;
    int tid = threadIdx.x;
    if (tid < 65) off[tid] = offg[b * OFFS + half * 64 + tid];
    __syncthreads();
    int e0 = off[0], cnt = off[64] - e0;
    const int* ptr = srow + (size_t)b * CAPB + e0;
    for (int s = tid; s < cnt; s += 256) sidx[s] = ptr[s];
    __syncthreads();

    int wid = tid >> 6, lane = tid & 63;
    int sg = lane >> 3, sl = lane & 7;
    const uint4* hs8 = (const uint4*)hs;         // row = 8 x uint4 (128 B)
    #pragma unroll
    for (int k = 0; k < 2; ++k) {
        int n = k * 32 + wid * 8 + sg;           // node within half
        int g = b * BKN + half * 64 + n;
        if (g < NN) {
            float4 lo0 = {}, hi0 = {}, lo1 = {}, hi1 = {};
            float4 lo2 = {}, hi2 = {}, lo3 = {}, hi3 = {};
            bacc8(lo0, hi0, hs8[(size_t)g * 8 + sl]);      // self loop
            int e = off[n] - e0, ee = off[n + 1] - e0;
            for (; e + 8 <= ee; e += 8) {
                int r0 = sidx[e + 0], r1 = sidx[e + 1];
                int r2 = sidx[e + 2], r3 = sidx[e + 3];
                int r4 = sidx[e + 4], r5 = sidx[e + 5];
                int r6 = sidx[e + 6], r7 = sidx[e + 7];
                uint4 v0 = hs8[(size_t)r0 * 8 + sl];
                uint4 v1 = hs8[(size_t)r1 * 8 + sl];
                uint4 v2 = hs8[(size_t)r2 * 8 + sl];
                uint4 v3 = hs8[(size_t)r3 * 8 + sl];
                uint4 v4 = hs8[(size_t)r4 * 8 + sl];
                uint4 v5 = hs8[(size_t)r5 * 8 + sl];
                uint4 v6 = hs8[(size_t)r6 * 8 + sl];
                uint4 v7 = hs8[(size_t)r7 * 8 + sl];
                bacc8(lo0, hi0, v0); bacc8(lo1, hi1, v1);
                bacc8(lo2, hi2, v2); bacc8(lo3, hi3, v3);
                bacc8(lo0, hi0, v4); bacc8(lo1, hi1, v5);
                bacc8(lo2, hi2, v6); bacc8(lo3, hi3, v7);
            }
            if (e + 4 <= ee) {
                int r0 = sidx[e + 0], r1 = sidx[e + 1];
                int r2 = sidx[e + 2], r3 = sidx[e + 3];
                uint4 v0 = hs8[(size_t)r0 * 8 + sl];
                uint4 v1 = hs8[(size_t)r1 * 8 + sl];
                uint4 v2 = hs8[(size_t)r2 * 8 + sl];
                uint4 v3 = hs8[(size_t)r3 * 8 + sl];
                bacc8(lo0, hi0, v0); bacc8(lo1, hi1, v1);
                bacc8(lo2, hi2, v2); bacc8(lo3, hi3, v3);
                e += 4;
            }
            for (; e < ee; ++e)
                bacc8(lo0, hi0, hs8[(size_t)sidx[e] * 8 + sl]);
            lo0.x += lo1.x + lo2.x + lo3.x;  hi0.x += hi1.x + hi2.x + hi3.x;
            lo0.y += lo1.y + lo2.y + lo3.y;  hi0.y += hi1.y + hi2.y + hi3.y;
            lo0.z += lo1.z + lo2.z + lo3.z;  hi0.z += hi1.z + hi2.z + hi3.z;
            lo0.w += lo1.w + lo2.w + lo3.w;  hi0.w += hi1.w + hi2.w + hi3.w;
            float d = dinv[g];
            float4 bb0 = ((const float4*)bias)[sl * 2];
            float4 bb1 = ((const float4*)bias)[sl * 2 + 1];
            float4 o0, o1;                                   // feats 8sl..8sl+7
            o0.x = fmaxf(fmaf(lo0.x, d, bb0.x), 0.f);
            o0.y = fmaxf(fmaf(hi0.x, d, bb0.y), 0.f);
            o0.z = fmaxf(fmaf(lo0.y, d, bb0.z), 0.f);
            o0.w = fmaxf(fmaf(hi0.y, d, bb0.w), 0.f);
            o1.x = fmaxf(fmaf(lo0.z, d, bb1.x), 0.f);
            o1.y = fmaxf(fmaf(hi0.z, d, bb1.y), 0.f);
            o1.z = fmaxf(fmaf(lo0.w, d, bb1.z), 0.f);
            o1.w = fmaxf(fmaf(hi0.w, d, bb1.w), 0.f);
            uint4 pk;
            pk.x = pk2(o0.x, o0.y);
            pk.y = pk2(o0.z, o0.w);
            pk.z = pk2(o1.x, o1.y);
            pk.w = pk2(o1.z, o1.w);
            ((uint4*)hb_out)[(size_t)g * 8 + sl] = pk;
        }
    }
}

// ---------------- row-major bf16 GEMM via MFMA (64-dim K) ----------------
// Block = 64 rows, 256 threads = 4 waves; wave = 16-row tile, NCT col tiles.
// FINAL=0: hsb_out[r][c] = bf16(acc * dinv[r])     (next layer's table)
// FINAL=1: f_out[r][c]   = acc + biasB[c]          (classifier, c < 40)
template <int FINAL>
__global__ __launch_bounds__(256) void gemm_rows(const unsigned short* __restrict__ hb,
                                                 const unsigned short* __restrict__ Wt,
                                                 const float* __restrict__ dinv,
                                                 const float* __restrict__ biasB,
                                                 unsigned short* __restrict__ hsb_out,
                                                 float* __restrict__ f_out) {
    __shared__ float sdv[64];
    int tid = threadIdx.x;
    int rbase = blockIdx.x * 64;
    if (!FINAL && tid < 64) {
        int r = rbase + tid;
        sdv[tid] = (r < NN) ? dinv[r] : 0.f;
    }
    int wid = tid >> 6, lane = tid & 63;
    int lm = lane & 15, lg = lane >> 4;
    int ra = rbase + wid * 16 + lm; if (ra >= NN) ra = NN - 1;
    bf16x8 af[2];
    #pragma unroll
    for (int kh = 0; kh < 2; ++kh)
        af[kh] = __builtin_bit_cast(bf16x8,
                    ((const uint4*)hb)[(size_t)ra * 8 + kh * 4 + lg]);
    constexpr int NCT = FINAL ? 3 : 4;
    f32x4 acc[NCT];
    #pragma unroll
    for (int ct = 0; ct < NCT; ++ct) {
        acc[ct] = (f32x4){0.f, 0.f, 0.f, 0.f};
        #pragma unroll
        for (int kh = 0; kh < 2; ++kh) {
            bf16x8 bf = __builtin_bit_cast(bf16x8,
                *(const uint4*)(Wt + (size_t)(ct * 16 + lm) * 64 + kh * 32 + lg * 8));
            acc[ct] = __builtin_amdgcn_mfma_f32_16x16x32_bf16(af[kh], bf, acc[ct], 0, 0, 0);
        }
    }
    if (!FINAL) __syncthreads();
    #pragma unroll
    for (int ct = 0; ct < NCT; ++ct) {
        if (!FINAL) {
            #pragma unroll
            for (int rg = 0; rg < 4; ++rg) {
                int rloc = wid * 16 + lg * 4 + rg;
                int r = rbase + rloc;
                if (r < NN)
                    hsb_out[(size_t)r * NH + ct * 16 + lm] = f2bf(acc[ct][rg] * sdv[rloc]);
            }
        } else {
            int c = ct * 16 + lm;
            if (c < NC) {
                float bb = biasB[c];
                #pragma unroll
                for (int rg = 0; rg < 4; ++rg) {
                    int r = rbase + wid * 16 + lg * 4 + rg;
                    if (r < NN)
                        f_out[(size_t)r * NC + c] = acc[ct][rg] + bb;
                }
            }
        }
    }
}

// ---------------- launch ----------------

extern "C" void kernel_launch(void* const* d_in, const int* in_sizes, int n_in,
                              void* d_out, int out_size, void* d_ws, size_t ws_size,
                              hipStream_t stream) {
    const float* x  = (const float*)d_in[0];
    const int* ei   = (const int*)d_in[1];      // [2, NE]
    const int* row  = ei;
    const int* col  = ei + NE;
    const float* W1 = (const float*)d_in[2];
    const float* b1 = (const float*)d_in[3];
    const float* W2 = (const float*)d_in[4];
    const float* b2 = (const float*)d_in[5];
    const float* Wc = (const float*)d_in[6];
    const float* bc = (const float*)d_in[7];
    float* out = (float*)d_out;

    char* ws = (char*)d_ws;
    size_t off = 0;
    auto alloc = [&](size_t bytes) {
        void* p = ws + off;
        off = (off + bytes + 255) & ~(size_t)255;
        return p;
    };
    int*   gcnt = (int*)alloc((size_t)NBK * 4);
    int*   offg = (int*)alloc((size_t)NBK * OFFS * 4);
    float* dinv = (float*)alloc((size_t)NN * 4);
    unsigned int* encs = (unsigned int*)alloc((size_t)NBK * CAPB * 4);   // 8 MB
    unsigned short* tabA = (unsigned short*)alloc((size_t)NN * NH * 2);  // bf16 table A
    unsigned short* tabB = (unsigned short*)alloc((size_t)NN * NH * 2);  // bf16 table B
    unsigned short* Wt1  = (unsigned short*)alloc((size_t)64 * 128 * 2); // bf16 W1^T
    unsigned short* Wt2  = (unsigned short*)alloc((size_t)64 * 64 * 2);  // bf16 W2^T
    unsigned short* Wtc  = (unsigned short*)alloc((size_t)48 * 64 * 2);  // bf16 Wc^T padded

    const int GB = (NN + 63) / 64;               // 1563

    prep_wt<<<64, 256, 0, stream>>>(W1, W2, Wc, Wt1, Wt2, Wtc, gcnt);
    bucket_scatter<<<NCHB, 256, 0, stream>>>(row, col, gcnt, encs);
    csr_sort<<<NBK, 256, 0, stream>>>(encs, gcnt, offg, dinv);

    // hsb1 = bf16((x @ W1) * dinv)       [tabA]
    gemm1_mfma<<<GB, 256, 0, stream>>>(x, Wt1, dinv, tabA);
    // h1 = relu(dinv*agg(hsb1) + b1)     [tabB]
    agg_bucket<<<NBK * 2, 256, 0, stream>>>(tabA, (const int*)encs, offg, dinv, b1, tabB);
    // hsb2 = bf16((h1 @ W2) * dinv)      [tabA]
    gemm_rows<0><<<GB, 256, 0, stream>>>(tabB, Wt2, dinv, nullptr, tabA, nullptr);
    // h2 = relu(dinv*agg(hsb2) + b2)     [tabB]
    agg_bucket<<<NBK * 2, 256, 0, stream>>>(tabA, (const int*)encs, offg, dinv, b2, tabB);
    // out = h2 @ Wc + bc
    gemm_rows<1><<<GB, 256, 0, stream>>>(tabB, Wtc, nullptr, bc, nullptr, out);
}